// Round 1
// baseline (548.530 us; speedup 1.0000x reference)
//
#include <hip/hip_runtime.h>
#include <cstdint>
#include <cstddef>

// ONLSTM cell: B=4096, D=1024, U=1024.
// pre = [X|H] @ [[W_all],[U_all]] + b_all   -> [4096, 6144], fp32 via split-fp16 MFMA
// then softmax(zft/zit, axis=-1), cumsum over axis 0 (batch), elementwise epilogue.

typedef _Float16 half8 __attribute__((ext_vector_type(8)));
typedef float f32x4 __attribute__((ext_vector_type(4)));

__device__ __forceinline__ void async16(const _Float16* g, _Float16* l) {
  __builtin_amdgcn_global_load_lds(
      (const __attribute__((address_space(1))) void*)g,
      (__attribute__((address_space(3))) void*)l, 16, 0, 0);
}

// ---------------------------------------------------------------------------
// A conversion: Ah[b][k] (k<1024 -> X, else H) split into fp16 hi+lo.
__global__ void convert_A(const float* __restrict__ X, const float* __restrict__ H,
                          _Float16* __restrict__ Ahi, _Float16* __restrict__ Alo) {
  size_t idx = (size_t)blockIdx.x * 256 + threadIdx.x;   // < 4096*2048
  int k = (int)(idx & 2047);
  size_t b = idx >> 11;
  float v = (k < 1024) ? X[b * 1024 + k] : H[b * 1024 + (k - 1024)];
  _Float16 hi = (_Float16)v;
  Ahi[idx] = hi;
  Alo[idx] = (_Float16)(v - (float)hi);
}

// ---------------------------------------------------------------------------
// Weight conversion: Bt[n][k] = 64 * (s==0 ? Wg[k'][c] : Ug[k'][c]), transposed
// through LDS so both global read and write are coalesced. Split hi+lo.
struct Ptrs12 { const float* p[12]; };

__global__ void convert_B(Ptrs12 srcs, _Float16* __restrict__ Bhi, _Float16* __restrict__ Blo) {
  __shared__ float tile[64][65];
  int mat = blockIdx.x >> 8;        // 0..11 == g*2 + s
  int tl  = blockIdx.x & 255;
  int tr = tl >> 4, tc = tl & 15;   // tr: k-block, tc: c-block
  int g = mat >> 1, s = mat & 1;
  const float* src = srcs.p[mat];
  int t = threadIdx.x;
  int col = t & 63, r0 = t >> 6;
#pragma unroll
  for (int i = 0; i < 16; i++) {
    int row = i * 4 + r0;
    tile[row][col] = src[(size_t)(tr * 64 + row) * 1024 + tc * 64 + col];
  }
  __syncthreads();
#pragma unroll
  for (int i = 0; i < 16; i++) {
    int c2 = i * 4 + r0, k2 = col;
    float v = tile[k2][c2] * 64.0f;     // x64: keep lo limb out of fp16 subnormals
    _Float16 hi = (_Float16)v;
    size_t n  = (size_t)g * 1024 + tc * 64 + c2;
    size_t kk = (size_t)s * 1024 + tr * 64 + k2;
    size_t o = n * 2048 + kk;
    Bhi[o] = hi;
    Blo[o] = (_Float16)(v - (float)hi);
  }
}

struct Ptrs6 { const float* p[6]; };
__global__ void build_bias(Ptrs6 bs, float* __restrict__ b_all) {
  int n = blockIdx.x * 256 + threadIdx.x;   // < 6144
  b_all[n] = bs.p[n >> 10][n & 1023];
}

// ---------------------------------------------------------------------------
// Split-fp16 GEMM: pre[M=4096, N=6144] = A[M,2048] @ Bt[N,2048]^T / 64 + bias
// 128x128 block tile, BK=32, 4 waves of 64x64, 3 MFMA products per tile pair.
__global__ __launch_bounds__(256) void gemm_split(
    const _Float16* __restrict__ Ah, const _Float16* __restrict__ Al,
    const _Float16* __restrict__ Bh, const _Float16* __restrict__ Bl,
    const float* __restrict__ b_all, float* __restrict__ pre) {
  __shared__ _Float16 lds[4 * 128 * 32];   // 32 KB: Ahi, Alo, Bhi, Blo tiles
  _Float16* sAh = lds;
  _Float16* sAl = lds + 4096;
  _Float16* sBh = lds + 8192;
  _Float16* sBl = lds + 12288;
  const int t = threadIdx.x;
  const int lane = t & 63;
  const int wave = t >> 6;
  const int waveM = wave >> 1, waveN = wave & 1;
  const int mTile = blockIdx.y, nTile = blockIdx.x;
  const size_t baseA = (size_t)mTile * 128 * 2048;
  const size_t baseB = (size_t)nTile * 128 * 2048;
  const int kgrp = lane >> 4;     // 0..3 -> k offset kgrp*8
  const int frow = lane & 15;

  f32x4 acc[4][4] = {};

  for (int ks = 0; ks < 64; ks++) {        // 2048 / 32
    const int k0 = ks * 32;
    // stage 4 tiles via global_load_lds (16B/lane), XOR-swizzled segments
#pragma unroll
    for (int q = 0; q < 2; q++) {
      int slot = q * 256 + t;
      int r = slot >> 2;
      int sg = slot & 3;
      int sig = sg ^ ((r >> 1) & 3);       // swizzle (self-inverse)
      size_t go = (size_t)r * 2048 + k0 + sig * 8;
      async16(Ah + baseA + go, sAh + slot * 8);
      async16(Al + baseA + go, sAl + slot * 8);
      async16(Bh + baseB + go, sBh + slot * 8);
      async16(Bl + baseB + go, sBl + slot * 8);
    }
    __syncthreads();

    half8 ah[4], al[4], bh[4], bl[4];
#pragma unroll
    for (int mi = 0; mi < 4; mi++) {
      int r = waveM * 64 + mi * 16 + frow;
      int ps = kgrp ^ ((r >> 1) & 3);
      int off = r * 32 + ps * 8;
      ah[mi] = *(const half8*)(sAh + off);
      al[mi] = *(const half8*)(sAl + off);
    }
#pragma unroll
    for (int ni = 0; ni < 4; ni++) {
      int r = waveN * 64 + ni * 16 + frow;
      int ps = kgrp ^ ((r >> 1) & 3);
      int off = r * 32 + ps * 8;
      bh[ni] = *(const half8*)(sBh + off);
      bl[ni] = *(const half8*)(sBl + off);
    }
#pragma unroll
    for (int mi = 0; mi < 4; mi++)
#pragma unroll
      for (int ni = 0; ni < 4; ni++) {
        acc[mi][ni] = __builtin_amdgcn_mfma_f32_16x16x32_f16(ah[mi], bh[ni], acc[mi][ni], 0, 0, 0);
        acc[mi][ni] = __builtin_amdgcn_mfma_f32_16x16x32_f16(ah[mi], bl[ni], acc[mi][ni], 0, 0, 0);
        acc[mi][ni] = __builtin_amdgcn_mfma_f32_16x16x32_f16(al[mi], bh[ni], acc[mi][ni], 0, 0, 0);
      }
    __syncthreads();
  }

  // epilogue: C/D layout col=lane&15, row=(lane>>4)*4+j (m89-verified)
#pragma unroll
  for (int ni = 0; ni < 4; ni++) {
    int col = nTile * 128 + waveN * 64 + ni * 16 + frow;
    float bias = b_all[col];
#pragma unroll
    for (int mi = 0; mi < 4; mi++) {
      int rbase = mTile * 128 + waveM * 64 + mi * 16 + kgrp * 4;
#pragma unroll
      for (int j = 0; j < 4; j++)
        pre[(size_t)(rbase + j) * 6144 + col] = acc[mi][ni][j] * (1.0f / 64.0f) + bias;
    }
  }
}

// ---------------------------------------------------------------------------
// Row softmax (in place over zft/zit region of pre) + per-chunk column sums.
// 16 rows per block (chunk), 4 waves x 4 rows each, 1 wave per row at a time.
__global__ void softmax_partials(float* __restrict__ pre, float* __restrict__ partials) {
  __shared__ float colsum[1024];
  int m = blockIdx.x >> 8;          // 0: zft, 1: zit
  int ch = blockIdx.x & 255;        // chunk of 16 rows
  int t = threadIdx.x;
  int wave = t >> 6, lane = t & 63;
  for (int i = t; i < 1024; i += 256) colsum[i] = 0.f;
  __syncthreads();
  float colacc[16];
#pragma unroll
  for (int j = 0; j < 16; j++) colacc[j] = 0.f;
  for (int rr = 0; rr < 4; rr++) {
    int b = ch * 16 + wave * 4 + rr;
    float* row = pre + (size_t)b * 6144 + (4 + m) * 1024;
    float v[16];
    float mx = -3.4e38f;
#pragma unroll
    for (int j = 0; j < 16; j++) { v[j] = row[lane + 64 * j]; mx = fmaxf(mx, v[j]); }
#pragma unroll
    for (int off = 32; off > 0; off >>= 1) mx = fmaxf(mx, __shfl_xor(mx, off, 64));
    float sum = 0.f;
#pragma unroll
    for (int j = 0; j < 16; j++) { v[j] = __expf(v[j] - mx); sum += v[j]; }
#pragma unroll
    for (int off = 32; off > 0; off >>= 1) sum += __shfl_xor(sum, off, 64);
    float inv = 1.f / sum;
#pragma unroll
    for (int j = 0; j < 16; j++) {
      float p = v[j] * inv;
      row[lane + 64 * j] = p;
      colacc[j] += p;
    }
  }
#pragma unroll
  for (int j = 0; j < 16; j++) atomicAdd(&colsum[lane + 64 * j], colacc[j]);
  __syncthreads();
  for (int i = t; i < 1024; i += 256)
    partials[((size_t)m * 256 + ch) * 1024 + i] = colsum[i];
}

// Exclusive scan of chunk partials along the 256 chunks, per (matrix, column).
__global__ void scan_partials(const float* __restrict__ partials, float* __restrict__ offsets) {
  int t = blockIdx.x * 256 + threadIdx.x;   // 0..2047
  int m = t >> 10, c = t & 1023;
  float run = 0.f;
  for (int ch = 0; ch < 256; ch++) {
    size_t idx = ((size_t)m * 256 + ch) * 1024 + c;
    offsets[idx] = run;
    run += partials[idx];
  }
}

// Final: per (chunk, 256-col tile), walk 16 rows accumulating the cumsum,
// apply gates, write hidden and cell.
__global__ void onlstm_final(const float* __restrict__ pre, const float* __restrict__ cprev,
                             const float* __restrict__ offsets, float* __restrict__ out) {
  int ch = blockIdx.x >> 2;
  int c = (blockIdx.x & 3) * 256 + threadIdx.x;
  float runf = offsets[(size_t)ch * 1024 + c];
  float runi = offsets[(size_t)(256 + ch) * 1024 + c];
  for (int r = 0; r < 16; r++) {
    int b = ch * 16 + r;
    const float* row = pre + (size_t)b * 6144;
    float zf = row[c], zi = row[1024 + c], zo = row[2048 + c], zc = row[3072 + c];
    float pf = row[4096 + c], pi = row[5120 + c];
    runf += pf; runi += pi;
    float ft = runf, it = 1.f - runi;
    float f  = 1.f / (1.f + __expf(-zf));
    float ii = 1.f / (1.f + __expf(-zi));
    float o  = 1.f / (1.f + __expf(-zo));
    float chat = tanhf(zc);
    float omega = ft * it;
    float fhat = f * omega + (ft - omega);
    float ihat = ii * omega + (it - omega);
    float cell = fhat * cprev[(size_t)b * 1024 + c] + ihat * chat;
    float hidden = o * tanhf(cell);
    out[(size_t)b * 1024 + c] = hidden;
    out[(size_t)4194304 + (size_t)b * 1024 + c] = cell;   // 4096*1024
  }
}

// ---------------------------------------------------------------------------
extern "C" void kernel_launch(void* const* d_in, const int* in_sizes, int n_in,
                              void* d_out, int out_size, void* d_ws, size_t ws_size,
                              hipStream_t stream) {
  const float* X = (const float*)d_in[0];
  const float* H = (const float*)d_in[1];
  const float* C = (const float*)d_in[2];

  char* ws = (char*)d_ws;
  float*    pre      = (float*)(ws);                      //  96 MB
  _Float16* Ahi      = (_Float16*)(ws + 100663296);       //  16 MB
  _Float16* Alo      = (_Float16*)(ws + 117440512);       //  16 MB
  _Float16* Bhi      = (_Float16*)(ws + 134217728);       //  24 MB
  _Float16* Blo      = (_Float16*)(ws + 159383552);       //  24 MB
  float*    b_all    = (float*)(ws + 184549376);          //  24 KB
  float*    partials = (float*)(ws + 184573952);          //   2 MB
  float*    offsets  = (float*)(ws + 186671104);          //   2 MB

  convert_A<<<32768, 256, 0, stream>>>(X, H, Ahi, Alo);

  Ptrs12 w;
  for (int g = 0; g < 6; g++) {
    w.p[2 * g]     = (const float*)d_in[3 + 3 * g];   // Wg
    w.p[2 * g + 1] = (const float*)d_in[4 + 3 * g];   // Ug
  }
  convert_B<<<3072, 256, 0, stream>>>(w, Bhi, Blo);

  Ptrs6 bs;
  for (int g = 0; g < 6; g++) bs.p[g] = (const float*)d_in[5 + 3 * g];
  build_bias<<<24, 256, 0, stream>>>(bs, b_all);

  gemm_split<<<dim3(48, 32), 256, 0, stream>>>(Ahi, Alo, Bhi, Blo, b_all, pre);

  softmax_partials<<<512, 256, 0, stream>>>(pre, partials);
  scan_partials<<<8, 256, 0, stream>>>(partials, offsets);
  onlstm_final<<<1024, 256, 0, stream>>>(pre, C, offsets, (float*)d_out);
}

// Round 2
// 484.697 us; speedup vs baseline: 1.1317x; 1.1317x over previous
//
#include <hip/hip_runtime.h>
#include <cstdint>
#include <cstddef>

// ONLSTM cell: B=4096, D=1024, U=1024.
// pre = [X|H] @ [[W_all],[U_all]] + b_all   -> [4096, 6144] fp32.
//   cols 0..4095   (zf,zi,zo,zc): single-product fp16 MFMA (sigmoid/tanh tolerate 1e-3)
//   cols 4096..6143 (zft,zit):    3-product split-fp16 (softmax->cumsum amplifies ~30x)
// then softmax(zft/zit, axis=-1), cumsum over axis 0 (batch), elementwise epilogue.

typedef _Float16 half8  __attribute__((ext_vector_type(8)));
typedef _Float16 half4v __attribute__((ext_vector_type(4)));
typedef _Float16 half2v __attribute__((ext_vector_type(2)));
typedef float f32x4 __attribute__((ext_vector_type(4)));

__device__ __forceinline__ void async16(const _Float16* g, _Float16* l) {
  __builtin_amdgcn_global_load_lds(
      (const __attribute__((address_space(1))) void*)g,
      (__attribute__((address_space(3))) void*)l, 16, 0, 0);
}

struct Ptrs12 { const float* p[12]; };
struct Ptrs6  { const float* p[6];  };

// ---------------------------------------------------------------------------
// Merged prep: convert A (X|H -> fp16 hi/lo), convert+transpose B (x64 scale),
// build bias. Branch is block-uniform.
__global__ void prep(const float* __restrict__ X, const float* __restrict__ H,
                     Ptrs12 w, Ptrs6 bs,
                     _Float16* __restrict__ Ahi, _Float16* __restrict__ Alo,
                     _Float16* __restrict__ Bhi, _Float16* __restrict__ Blo,
                     float* __restrict__ b_all) {
  __shared__ float tile[64][65];
  const int blk = blockIdx.x;
  const int t = threadIdx.x;
  if (blk < 8192) {
    // ---- convert_A: 4 consecutive elements per thread (never crosses X/H split)
    size_t base = ((size_t)blk * 256 + t) * 4;       // < 4096*2048
    int k = (int)(base & 2047);
    size_t b = base >> 11;
    const float* src = (k < 1024) ? (X + b * 1024 + k) : (H + b * 1024 + (k - 1024));
    float4 v = *(const float4*)src;
    half4v hi = { (_Float16)v.x, (_Float16)v.y, (_Float16)v.z, (_Float16)v.w };
    half4v lo = { (_Float16)(v.x - (float)hi[0]), (_Float16)(v.y - (float)hi[1]),
                  (_Float16)(v.z - (float)hi[2]), (_Float16)(v.w - (float)hi[3]) };
    *(half4v*)(Ahi + base) = hi;
    *(half4v*)(Alo + base) = lo;
  } else if (blk < 11264) {
    // ---- convert_B: transpose 64x64 tile through LDS, split hi/lo, x64 scale
    int bb = blk - 8192;
    int mat = bb >> 8;                 // 0..11 == g*2 + s
    int tl = bb & 255;
    int tr = tl >> 4, tc = tl & 15;    // tr: k-block, tc: c-block
    int g = mat >> 1, s = mat & 1;
    const float* src = w.p[mat];
    int col = t & 63, r0 = t >> 6;
#pragma unroll
    for (int i = 0; i < 16; i++) {
      int row = i * 4 + r0;
      tile[row][col] = src[(size_t)(tr * 64 + row) * 1024 + tc * 64 + col];
    }
    __syncthreads();
    int kh = (t & 31) * 2, r8 = t >> 5;
#pragma unroll
    for (int i = 0; i < 8; i++) {
      int c2 = i * 8 + r8;
      float v0 = tile[kh][c2] * 64.0f;      // x64: keep lo limb out of fp16 subnormals
      float v1 = tile[kh + 1][c2] * 64.0f;
      _Float16 h0 = (_Float16)v0, h1 = (_Float16)v1;
      size_t n  = (size_t)g * 1024 + tc * 64 + c2;
      size_t kk = (size_t)s * 1024 + tr * 64 + kh;
      size_t o = n * 2048 + kk;
      *(half2v*)(Bhi + o) = half2v{ h0, h1 };
      *(half2v*)(Blo + o) = half2v{ (_Float16)(v0 - (float)h0), (_Float16)(v1 - (float)h1) };
    }
  } else {
    int n = (blk - 11264) * 256 + t;    // < 6144
    b_all[n] = bs.p[n >> 10][n & 1023];
  }
}

// ---------------------------------------------------------------------------
// GEMM: pre[M=4096, N=6144] = A[M,2048] @ Bt[N,2048]^T / 64 + bias
// 128x128 tile, BK=32, 4 waves of 64x64. FULL: 3 MFMA products (split-fp16).
template<bool FULL>
__device__ __forceinline__ void kloop(
    const _Float16* __restrict__ Ah, const _Float16* __restrict__ Al,
    const _Float16* __restrict__ Bh, const _Float16* __restrict__ Bl,
    _Float16* lds, size_t baseA, size_t baseB, int t, f32x4 (&acc)[4][4]) {
  _Float16* sAh = lds;
  _Float16* sBh = lds + 4096;
  _Float16* sAl = lds + 8192;
  _Float16* sBl = lds + 12288;
  const int lane = t & 63;
  const int wave = t >> 6;
  const int waveM = wave >> 1, waveN = wave & 1;
  const int kgrp = lane >> 4, frow = lane & 15;

  for (int ks = 0; ks < 64; ks++) {        // 2048 / 32
    const int k0 = ks * 32;
#pragma unroll
    for (int q = 0; q < 2; q++) {
      int slot = q * 256 + t;
      int r = slot >> 2;
      int sg = slot & 3;
      int sig = sg ^ ((r >> 1) & 3);       // XOR swizzle (self-inverse)
      size_t go = (size_t)r * 2048 + k0 + sig * 8;
      async16(Ah + baseA + go, sAh + slot * 8);
      async16(Bh + baseB + go, sBh + slot * 8);
      if constexpr (FULL) {
        async16(Al + baseA + go, sAl + slot * 8);
        async16(Bl + baseB + go, sBl + slot * 8);
      }
    }
    __syncthreads();

    half8 ah[4], bh[4], al[4], bl[4];
#pragma unroll
    for (int mi = 0; mi < 4; mi++) {
      int r = waveM * 64 + mi * 16 + frow;
      int ps = kgrp ^ ((r >> 1) & 3);
      int off = r * 32 + ps * 8;
      ah[mi] = *(const half8*)(sAh + off);
      if constexpr (FULL) al[mi] = *(const half8*)(sAl + off);
    }
#pragma unroll
    for (int ni = 0; ni < 4; ni++) {
      int r = waveN * 64 + ni * 16 + frow;
      int ps = kgrp ^ ((r >> 1) & 3);
      int off = r * 32 + ps * 8;
      bh[ni] = *(const half8*)(sBh + off);
      if constexpr (FULL) bl[ni] = *(const half8*)(sBl + off);
    }
#pragma unroll
    for (int mi = 0; mi < 4; mi++)
#pragma unroll
      for (int ni = 0; ni < 4; ni++) {
        acc[mi][ni] = __builtin_amdgcn_mfma_f32_16x16x32_f16(ah[mi], bh[ni], acc[mi][ni], 0, 0, 0);
        if constexpr (FULL) {
          acc[mi][ni] = __builtin_amdgcn_mfma_f32_16x16x32_f16(ah[mi], bl[ni], acc[mi][ni], 0, 0, 0);
          acc[mi][ni] = __builtin_amdgcn_mfma_f32_16x16x32_f16(al[mi], bh[ni], acc[mi][ni], 0, 0, 0);
        }
      }
    __syncthreads();
  }
}

__global__ __launch_bounds__(256) void gemm_split(
    const _Float16* __restrict__ Ah, const _Float16* __restrict__ Al,
    const _Float16* __restrict__ Bh, const _Float16* __restrict__ Bl,
    const float* __restrict__ b_all, float* __restrict__ pre) {
  __shared__ _Float16 lds[16384];   // 32 KB
  const int t = threadIdx.x;
  const int mTile = blockIdx.y, nTile = blockIdx.x;
  const size_t baseA = (size_t)mTile * 128 * 2048;
  const size_t baseB = (size_t)nTile * 128 * 2048;

  f32x4 acc[4][4] = {};
  if (nTile >= 32) kloop<true >(Ah, Al, Bh, Bl, lds, baseA, baseB, t, acc);
  else             kloop<false>(Ah, Al, Bh, Bl, lds, baseA, baseB, t, acc);

  // epilogue: C/D layout col=lane&15, row=(lane>>4)*4+j (m89-verified)
  const int lane = t & 63;
  const int wave = t >> 6;
  const int waveM = wave >> 1, waveN = wave & 1;
  const int kgrp = lane >> 4, frow = lane & 15;
#pragma unroll
  for (int ni = 0; ni < 4; ni++) {
    int col = nTile * 128 + waveN * 64 + ni * 16 + frow;
    float bias = b_all[col];
#pragma unroll
    for (int mi = 0; mi < 4; mi++) {
      int rbase = mTile * 128 + waveM * 64 + mi * 16 + kgrp * 4;
#pragma unroll
      for (int j = 0; j < 4; j++)
        pre[(size_t)(rbase + j) * 6144 + col] = acc[mi][ni][j] * (1.0f / 64.0f) + bias;
    }
  }
}

// ---------------------------------------------------------------------------
// Row softmax (in place over zft/zit region of pre) + per-chunk column sums.
__global__ void softmax_partials(float* __restrict__ pre, float* __restrict__ partials) {
  __shared__ float colsum[1024];
  int m = blockIdx.x >> 8;          // 0: zft, 1: zit
  int ch = blockIdx.x & 255;        // chunk of 16 rows
  int t = threadIdx.x;
  int wave = t >> 6, lane = t & 63;
  for (int i = t; i < 1024; i += 256) colsum[i] = 0.f;
  __syncthreads();
  float colacc[16];
#pragma unroll
  for (int j = 0; j < 16; j++) colacc[j] = 0.f;
  for (int rr = 0; rr < 4; rr++) {
    int b = ch * 16 + wave * 4 + rr;
    float* row = pre + (size_t)b * 6144 + (4 + m) * 1024;
    float v[16];
    float mx = -3.4e38f;
#pragma unroll
    for (int j = 0; j < 16; j++) { v[j] = row[lane + 64 * j]; mx = fmaxf(mx, v[j]); }
#pragma unroll
    for (int off = 32; off > 0; off >>= 1) mx = fmaxf(mx, __shfl_xor(mx, off, 64));
    float sum = 0.f;
#pragma unroll
    for (int j = 0; j < 16; j++) { v[j] = __expf(v[j] - mx); sum += v[j]; }
#pragma unroll
    for (int off = 32; off > 0; off >>= 1) sum += __shfl_xor(sum, off, 64);
    float inv = 1.f / sum;
#pragma unroll
    for (int j = 0; j < 16; j++) {
      float p = v[j] * inv;
      row[lane + 64 * j] = p;
      colacc[j] += p;
    }
  }
#pragma unroll
  for (int j = 0; j < 16; j++) atomicAdd(&colsum[lane + 64 * j], colacc[j]);
  __syncthreads();
  for (int i = t; i < 1024; i += 256)
    partials[((size_t)m * 256 + ch) * 1024 + i] = colsum[i];
}

// Exclusive scan over 256 chunks per (matrix, column): one wave per column.
__global__ void scan_partials(const float* __restrict__ partials, float* __restrict__ offsets) {
  int col = blockIdx.x * 4 + (threadIdx.x >> 6);   // 0..2047 over 2 matrices
  int lane = threadIdx.x & 63;
  int m = col >> 10, c = col & 1023;
  size_t base = (size_t)m * 256 * 1024 + c;
  float v[4];
  float s = 0.f;
#pragma unroll
  for (int j = 0; j < 4; j++) {
    v[j] = partials[base + (size_t)(lane * 4 + j) * 1024];
    s += v[j];
  }
  float incl = s;
#pragma unroll
  for (int off = 1; off < 64; off <<= 1) {
    float o = __shfl_up(incl, off, 64);
    if (lane >= off) incl += o;
  }
  float run = incl - s;                            // exclusive prefix
#pragma unroll
  for (int j = 0; j < 4; j++) {
    offsets[base + (size_t)(lane * 4 + j) * 1024] = run;
    run += v[j];
  }
}

// Final: per (chunk, 256-col tile), walk 16 rows accumulating the cumsum,
// apply gates, write hidden and cell.
__global__ void onlstm_final(const float* __restrict__ pre, const float* __restrict__ cprev,
                             const float* __restrict__ offsets, float* __restrict__ out) {
  int ch = blockIdx.x >> 2;
  int c = (blockIdx.x & 3) * 256 + threadIdx.x;
  float runf = offsets[(size_t)ch * 1024 + c];
  float runi = offsets[(size_t)(256 + ch) * 1024 + c];
  for (int r = 0; r < 16; r++) {
    int b = ch * 16 + r;
    const float* row = pre + (size_t)b * 6144;
    float zf = row[c], zi = row[1024 + c], zo = row[2048 + c], zc = row[3072 + c];
    float pf = row[4096 + c], pi = row[5120 + c];
    runf += pf; runi += pi;
    float ft = runf, it = 1.f - runi;
    float f  = 1.f / (1.f + __expf(-zf));
    float ii = 1.f / (1.f + __expf(-zi));
    float o  = 1.f / (1.f + __expf(-zo));
    float chat = tanhf(zc);
    float omega = ft * it;
    float fhat = f * omega + (ft - omega);
    float ihat = ii * omega + (it - omega);
    float cell = fhat * cprev[(size_t)b * 1024 + c] + ihat * chat;
    float hidden = o * tanhf(cell);
    out[(size_t)b * 1024 + c] = hidden;
    out[(size_t)4194304 + (size_t)b * 1024 + c] = cell;   // 4096*1024
  }
}

// ---------------------------------------------------------------------------
extern "C" void kernel_launch(void* const* d_in, const int* in_sizes, int n_in,
                              void* d_out, int out_size, void* d_ws, size_t ws_size,
                              hipStream_t stream) {
  const float* X = (const float*)d_in[0];
  const float* H = (const float*)d_in[1];
  const float* C = (const float*)d_in[2];

  char* ws = (char*)d_ws;
  float*    pre      = (float*)(ws);                      //  96 MB
  _Float16* Ahi      = (_Float16*)(ws + 100663296);       //  16 MB
  _Float16* Alo      = (_Float16*)(ws + 117440512);       //  16 MB
  _Float16* Bhi      = (_Float16*)(ws + 134217728);       //  24 MB
  _Float16* Blo      = (_Float16*)(ws + 159383552);       //  24 MB
  float*    b_all    = (float*)(ws + 184549376);          //  24 KB
  float*    partials = (float*)(ws + 184573952);          //   2 MB
  float*    offsets  = (float*)(ws + 186671104);          //   2 MB

  Ptrs12 w;
  for (int g = 0; g < 6; g++) {
    w.p[2 * g]     = (const float*)d_in[3 + 3 * g];   // Wg
    w.p[2 * g + 1] = (const float*)d_in[4 + 3 * g];   // Ug
  }
  Ptrs6 bs;
  for (int g = 0; g < 6; g++) bs.p[g] = (const float*)d_in[5 + 3 * g];

  prep<<<11288, 256, 0, stream>>>(X, H, w, bs, Ahi, Alo, Bhi, Blo, b_all);
  gemm_split<<<dim3(48, 32), 256, 0, stream>>>(Ahi, Alo, Bhi, Blo, b_all, pre);
  softmax_partials<<<512, 256, 0, stream>>>(pre, partials);
  scan_partials<<<512, 256, 0, stream>>>(partials, offsets);
  onlstm_final<<<1024, 256, 0, stream>>>(pre, C, offsets, (float*)d_out);
}

// Round 3
// 356.735 us; speedup vs baseline: 1.5376x; 1.3587x over previous
//
#include <hip/hip_runtime.h>
#include <cstdint>
#include <cstddef>

// ONLSTM cell: B=4096, D=1024, U=1024.
// pre = [X|H] @ [[W_all],[U_all]] + b_all -> [4096, 6144] fp32, single-fp16 MFMA
// (m97 structure). Verified rounds 1-2: absmax is dominated by the fp32
// softmax/cumsum path (0.25 regardless of GEMM precision); single-fp16 GEMM
// adds ~0.03-0.2 vs threshold 1.55.
// Then softmax(zft/zit, axis=-1), cumsum over axis 0 (batch), elementwise epilogue.

typedef _Float16 half8  __attribute__((ext_vector_type(8)));
typedef _Float16 half4v __attribute__((ext_vector_type(4)));
typedef _Float16 half2v __attribute__((ext_vector_type(2)));
typedef float f32x4 __attribute__((ext_vector_type(4)));

__device__ __forceinline__ void async16(const _Float16* g, _Float16* l) {
  __builtin_amdgcn_global_load_lds(
      (const __attribute__((address_space(1))) void*)g,
      (__attribute__((address_space(3))) void*)l, 16, 0, 0);
}

struct Ptrs12 { const float* p[12]; };
struct Ptrs6  { const float* p[6];  };

// ---------------------------------------------------------------------------
// Merged prep: convert A (X|H -> fp16), convert+transpose B (x64 scale, fp16),
// build bias. Branch is block-uniform.
__global__ void prep(const float* __restrict__ X, const float* __restrict__ H,
                     Ptrs12 w, Ptrs6 bs,
                     _Float16* __restrict__ Ahi, _Float16* __restrict__ Bhi,
                     float* __restrict__ b_all) {
  __shared__ float tile[64][65];
  const int blk = blockIdx.x;
  const int t = threadIdx.x;
  if (blk < 8192) {
    // ---- convert_A: 4 consecutive elements per thread (never crosses X/H split)
    size_t base = ((size_t)blk * 256 + t) * 4;       // < 4096*2048
    int k = (int)(base & 2047);
    size_t b = base >> 11;
    const float* src = (k < 1024) ? (X + b * 1024 + k) : (H + b * 1024 + (k - 1024));
    float4 v = *(const float4*)src;
    half4v hi = { (_Float16)v.x, (_Float16)v.y, (_Float16)v.z, (_Float16)v.w };
    *(half4v*)(Ahi + base) = hi;
  } else if (blk < 11264) {
    // ---- convert_B: transpose 64x64 tile through LDS, x64 scale (guard vs
    // fp16 subnormal flush in MFMA; /64 folded into epilogue)
    int bb = blk - 8192;
    int mat = bb >> 8;                 // 0..11 == g*2 + s
    int tl = bb & 255;
    int tr = tl >> 4, tc = tl & 15;    // tr: k-block, tc: c-block
    int g = mat >> 1, s = mat & 1;
    const float* src = w.p[mat];
    int col = t & 63, r0 = t >> 6;
#pragma unroll
    for (int i = 0; i < 16; i++) {
      int row = i * 4 + r0;
      tile[row][col] = src[(size_t)(tr * 64 + row) * 1024 + tc * 64 + col];
    }
    __syncthreads();
    int kh = (t & 31) * 2, r8 = t >> 5;
#pragma unroll
    for (int i = 0; i < 8; i++) {
      int c2 = i * 8 + r8;
      float v0 = tile[kh][c2] * 64.0f;
      float v1 = tile[kh + 1][c2] * 64.0f;
      size_t n  = (size_t)g * 1024 + tc * 64 + c2;
      size_t kk = (size_t)s * 1024 + tr * 64 + kh;
      *(half2v*)(Bhi + n * 2048 + kk) = half2v{ (_Float16)v0, (_Float16)v1 };
    }
  } else {
    int n = (blk - 11264) * 256 + t;    // < 6144
    b_all[n] = bs.p[n >> 10][n & 1023];
  }
}

// ---------------------------------------------------------------------------
// GEMM: pre[M=4096, N=6144] = A[M,2048] @ Bt[N,2048]^T / 64 + bias
// m97 structure: 128x128 tile, BK=32, 4 waves of 64x64, 16 KB LDS.
__global__ __launch_bounds__(256) void gemm_split(
    const _Float16* __restrict__ Ah, const _Float16* __restrict__ Bh,
    const float* __restrict__ b_all, float* __restrict__ pre) {
  __shared__ _Float16 lds[8192];   // 16 KB: A tile + B tile
  _Float16* sAh = lds;
  _Float16* sBh = lds + 4096;

  // GROUP_M=8 swizzle: 8 consecutive pids share one B tile (L2 reuse)
  const int pid = blockIdx.x;                 // 0..1535
  const int group = pid / (8 * 48);
  const int rem = pid % (8 * 48);
  const int mTile = group * 8 + (rem & 7);    // 0..31
  const int nTile = rem >> 3;                 // 0..47

  const int t = threadIdx.x;
  const int lane = t & 63;
  const int wave = t >> 6;
  const int waveM = wave >> 1, waveN = wave & 1;
  const int kgrp = lane >> 4, frow = lane & 15;
  const size_t baseA = (size_t)mTile * 128 * 2048;
  const size_t baseB = (size_t)nTile * 128 * 2048;

  f32x4 acc[4][4] = {};

  for (int ks = 0; ks < 64; ks++) {        // 2048 / 32
    const int k0 = ks * 32;
#pragma unroll
    for (int q = 0; q < 2; q++) {
      int slot = q * 256 + t;
      int r = slot >> 2;
      int sg = slot & 3;
      int sig = sg ^ ((r >> 1) & 3);       // XOR swizzle (self-inverse)
      size_t go = (size_t)r * 2048 + k0 + sig * 8;
      async16(Ah + baseA + go, sAh + slot * 8);
      async16(Bh + baseB + go, sBh + slot * 8);
    }
    __syncthreads();

    half8 ah[4], bh[4];
#pragma unroll
    for (int mi = 0; mi < 4; mi++) {
      int r = waveM * 64 + mi * 16 + frow;
      int ps = kgrp ^ ((r >> 1) & 3);
      ah[mi] = *(const half8*)(sAh + r * 32 + ps * 8);
    }
#pragma unroll
    for (int ni = 0; ni < 4; ni++) {
      int r = waveN * 64 + ni * 16 + frow;
      int ps = kgrp ^ ((r >> 1) & 3);
      bh[ni] = *(const half8*)(sBh + r * 32 + ps * 8);
    }
#pragma unroll
    for (int mi = 0; mi < 4; mi++)
#pragma unroll
      for (int ni = 0; ni < 4; ni++)
        acc[mi][ni] = __builtin_amdgcn_mfma_f32_16x16x32_f16(ah[mi], bh[ni], acc[mi][ni], 0, 0, 0);
    __syncthreads();
  }

  // epilogue: C/D layout col=lane&15, row=(lane>>4)*4+j (m89-verified)
#pragma unroll
  for (int ni = 0; ni < 4; ni++) {
    int col = nTile * 128 + waveN * 64 + ni * 16 + frow;
    float bias = b_all[col];
#pragma unroll
    for (int mi = 0; mi < 4; mi++) {
      int rbase = mTile * 128 + waveM * 64 + mi * 16 + kgrp * 4;
#pragma unroll
      for (int j = 0; j < 4; j++)
        pre[(size_t)(rbase + j) * 6144 + col] = acc[mi][ni][j] * (1.0f / 64.0f) + bias;
    }
  }
}

// ---------------------------------------------------------------------------
// Row softmax (in place over zft/zit region of pre) + per-chunk column sums.
__global__ void softmax_partials(float* __restrict__ pre, float* __restrict__ partials) {
  __shared__ float colsum[1024];
  int m = blockIdx.x >> 8;          // 0: zft, 1: zit
  int ch = blockIdx.x & 255;        // chunk of 16 rows
  int t = threadIdx.x;
  int wave = t >> 6, lane = t & 63;
  for (int i = t; i < 1024; i += 256) colsum[i] = 0.f;
  __syncthreads();
  float colacc[16];
#pragma unroll
  for (int j = 0; j < 16; j++) colacc[j] = 0.f;
  for (int rr = 0; rr < 4; rr++) {
    int b = ch * 16 + wave * 4 + rr;
    float* row = pre + (size_t)b * 6144 + (4 + m) * 1024;
    float v[16];
    float mx = -3.4e38f;
#pragma unroll
    for (int j = 0; j < 16; j++) { v[j] = row[lane + 64 * j]; mx = fmaxf(mx, v[j]); }
#pragma unroll
    for (int off = 32; off > 0; off >>= 1) mx = fmaxf(mx, __shfl_xor(mx, off, 64));
    float sum = 0.f;
#pragma unroll
    for (int j = 0; j < 16; j++) { v[j] = __expf(v[j] - mx); sum += v[j]; }
#pragma unroll
    for (int off = 32; off > 0; off >>= 1) sum += __shfl_xor(sum, off, 64);
    float inv = 1.f / sum;
#pragma unroll
    for (int j = 0; j < 16; j++) {
      float p = v[j] * inv;
      row[lane + 64 * j] = p;
      colacc[j] += p;
    }
  }
#pragma unroll
  for (int j = 0; j < 16; j++) atomicAdd(&colsum[lane + 64 * j], colacc[j]);
  __syncthreads();
  for (int i = t; i < 1024; i += 256)
    partials[((size_t)m * 256 + ch) * 1024 + i] = colsum[i];
}

// Exclusive scan over 256 chunks per (matrix, column): one wave per column.
__global__ void scan_partials(const float* __restrict__ partials, float* __restrict__ offsets) {
  int col = blockIdx.x * 4 + (threadIdx.x >> 6);   // 0..2047 over 2 matrices
  int lane = threadIdx.x & 63;
  int m = col >> 10, c = col & 1023;
  size_t base = (size_t)m * 256 * 1024 + c;
  float v[4];
  float s = 0.f;
#pragma unroll
  for (int j = 0; j < 4; j++) {
    v[j] = partials[base + (size_t)(lane * 4 + j) * 1024];
    s += v[j];
  }
  float incl = s;
#pragma unroll
  for (int off = 1; off < 64; off <<= 1) {
    float o = __shfl_up(incl, off, 64);
    if (lane >= off) incl += o;
  }
  float run = incl - s;                            // exclusive prefix
#pragma unroll
  for (int j = 0; j < 4; j++) {
    offsets[base + (size_t)(lane * 4 + j) * 1024] = run;
    run += v[j];
  }
}

// Final: per (chunk, 256-col tile), walk 16 rows accumulating the cumsum,
// apply gates, write hidden and cell.
__global__ void onlstm_final(const float* __restrict__ pre, const float* __restrict__ cprev,
                             const float* __restrict__ offsets, float* __restrict__ out) {
  int ch = blockIdx.x >> 2;
  int c = (blockIdx.x & 3) * 256 + threadIdx.x;
  float runf = offsets[(size_t)ch * 1024 + c];
  float runi = offsets[(size_t)(256 + ch) * 1024 + c];
  for (int r = 0; r < 16; r++) {
    int b = ch * 16 + r;
    const float* row = pre + (size_t)b * 6144;
    float zf = row[c], zi = row[1024 + c], zo = row[2048 + c], zc = row[3072 + c];
    float pf = row[4096 + c], pi = row[5120 + c];
    runf += pf; runi += pi;
    float ft = runf, it = 1.f - runi;
    float f  = 1.f / (1.f + __expf(-zf));
    float ii = 1.f / (1.f + __expf(-zi));
    float o  = 1.f / (1.f + __expf(-zo));
    float chat = tanhf(zc);
    float omega = ft * it;
    float fhat = f * omega + (ft - omega);
    float ihat = ii * omega + (it - omega);
    float cell = fhat * cprev[(size_t)b * 1024 + c] + ihat * chat;
    float hidden = o * tanhf(cell);
    out[(size_t)b * 1024 + c] = hidden;
    out[(size_t)4194304 + (size_t)b * 1024 + c] = cell;   // 4096*1024
  }
}

// ---------------------------------------------------------------------------
extern "C" void kernel_launch(void* const* d_in, const int* in_sizes, int n_in,
                              void* d_out, int out_size, void* d_ws, size_t ws_size,
                              hipStream_t stream) {
  const float* X = (const float*)d_in[0];
  const float* H = (const float*)d_in[1];
  const float* C = (const float*)d_in[2];

  char* ws = (char*)d_ws;
  float*    pre      = (float*)(ws);                      //  96 MB
  _Float16* Ahi      = (_Float16*)(ws + 100663296);       //  16 MB
  _Float16* Bhi      = (_Float16*)(ws + 117440512);       //  24 MB
  float*    b_all    = (float*)(ws + 142606336);          //  24 KB
  float*    partials = (float*)(ws + 142630912);          //   2 MB
  float*    offsets  = (float*)(ws + 144728064);          //   2 MB

  Ptrs12 w;
  for (int g = 0; g < 6; g++) {
    w.p[2 * g]     = (const float*)d_in[3 + 3 * g];   // Wg
    w.p[2 * g + 1] = (const float*)d_in[4 + 3 * g];   // Ug
  }
  Ptrs6 bs;
  for (int g = 0; g < 6; g++) bs.p[g] = (const float*)d_in[5 + 3 * g];

  prep<<<11288, 256, 0, stream>>>(X, H, w, bs, Ahi, Bhi, b_all);
  gemm_split<<<1536, 256, 0, stream>>>(Ahi, Bhi, b_all, pre);
  softmax_partials<<<512, 256, 0, stream>>>(pre, partials);
  scan_partials<<<512, 256, 0, stream>>>(partials, offsets);
  onlstm_final<<<1024, 256, 0, stream>>>(pre, C, offsets, (float*)d_out);
}

// Round 4
// 345.802 us; speedup vs baseline: 1.5863x; 1.0316x over previous
//
#include <hip/hip_runtime.h>
#include <cstdint>
#include <cstddef>

// ONLSTM cell: B=4096, D=1024, U=1024.
// pre = [X|H] @ [[W_all],[U_all]] + b_all -> [4096, 6144] fp32, single-fp16 MFMA
// (m97 structure). Verified R1-R3: absmax (0.25) is dominated by the fp32
// softmax/cumsum path regardless of GEMM precision; threshold 1.55.
// Then softmax(zft/zit, axis=-1), cumsum over axis 0 (batch), elementwise epilogue.
// R4: post-GEMM kernels vectorized to float4, atomics removed, CH=8 chunks.

typedef _Float16 half8  __attribute__((ext_vector_type(8)));
typedef _Float16 half4v __attribute__((ext_vector_type(4)));
typedef _Float16 half2v __attribute__((ext_vector_type(2)));
typedef float f32x4 __attribute__((ext_vector_type(4)));

__device__ __forceinline__ void async16(const _Float16* g, _Float16* l) {
  __builtin_amdgcn_global_load_lds(
      (const __attribute__((address_space(1))) void*)g,
      (__attribute__((address_space(3))) void*)l, 16, 0, 0);
}

struct Ptrs12 { const float* p[12]; };
struct Ptrs6  { const float* p[6];  };

// ---------------------------------------------------------------------------
// Merged prep: convert A (X|H -> fp16), convert+transpose B (x64 scale, fp16),
// build bias. Branch is block-uniform.
__global__ void prep(const float* __restrict__ X, const float* __restrict__ H,
                     Ptrs12 w, Ptrs6 bs,
                     _Float16* __restrict__ Ahi, _Float16* __restrict__ Bhi,
                     float* __restrict__ b_all) {
  __shared__ float tile[64][65];
  const int blk = blockIdx.x;
  const int t = threadIdx.x;
  if (blk < 8192) {
    // ---- convert_A: 4 consecutive elements per thread (never crosses X/H split)
    size_t base = ((size_t)blk * 256 + t) * 4;       // < 4096*2048
    int k = (int)(base & 2047);
    size_t b = base >> 11;
    const float* src = (k < 1024) ? (X + b * 1024 + k) : (H + b * 1024 + (k - 1024));
    float4 v = *(const float4*)src;
    half4v hi = { (_Float16)v.x, (_Float16)v.y, (_Float16)v.z, (_Float16)v.w };
    *(half4v*)(Ahi + base) = hi;
  } else if (blk < 11264) {
    // ---- convert_B: transpose 64x64 tile through LDS, x64 scale (guard vs
    // fp16 subnormal flush in MFMA; /64 folded into epilogue)
    int bb = blk - 8192;
    int mat = bb >> 8;                 // 0..11 == g*2 + s
    int tl = bb & 255;
    int tr = tl >> 4, tc = tl & 15;    // tr: k-block, tc: c-block
    int g = mat >> 1, s = mat & 1;
    const float* src = w.p[mat];
    int col = t & 63, r0 = t >> 6;
#pragma unroll
    for (int i = 0; i < 16; i++) {
      int row = i * 4 + r0;
      tile[row][col] = src[(size_t)(tr * 64 + row) * 1024 + tc * 64 + col];
    }
    __syncthreads();
    int kh = (t & 31) * 2, r8 = t >> 5;
#pragma unroll
    for (int i = 0; i < 8; i++) {
      int c2 = i * 8 + r8;
      float v0 = tile[kh][c2] * 64.0f;
      float v1 = tile[kh + 1][c2] * 64.0f;
      size_t n  = (size_t)g * 1024 + tc * 64 + c2;
      size_t kk = (size_t)s * 1024 + tr * 64 + kh;
      *(half2v*)(Bhi + n * 2048 + kk) = half2v{ (_Float16)v0, (_Float16)v1 };
    }
  } else {
    int n = (blk - 11264) * 256 + t;    // < 6144
    b_all[n] = bs.p[n >> 10][n & 1023];
  }
}

// ---------------------------------------------------------------------------
// GEMM: pre[M=4096, N=6144] = A[M,2048] @ Bt[N,2048]^T / 64 + bias
// m97 structure: 128x128 tile, BK=32, 4 waves of 64x64, 16 KB LDS.
__global__ __launch_bounds__(256) void gemm_split(
    const _Float16* __restrict__ Ah, const _Float16* __restrict__ Bh,
    const float* __restrict__ b_all, float* __restrict__ pre) {
  __shared__ _Float16 lds[8192];   // 16 KB: A tile + B tile
  _Float16* sAh = lds;
  _Float16* sBh = lds + 4096;

  // GROUP_M=8 swizzle: 8 consecutive pids share one B tile (L2 reuse)
  const int pid = blockIdx.x;                 // 0..1535
  const int group = pid / (8 * 48);
  const int rem = pid % (8 * 48);
  const int mTile = group * 8 + (rem & 7);    // 0..31
  const int nTile = rem >> 3;                 // 0..47

  const int t = threadIdx.x;
  const int lane = t & 63;
  const int wave = t >> 6;
  const int waveM = wave >> 1, waveN = wave & 1;
  const int kgrp = lane >> 4, frow = lane & 15;
  const size_t baseA = (size_t)mTile * 128 * 2048;
  const size_t baseB = (size_t)nTile * 128 * 2048;

  f32x4 acc[4][4] = {};

  for (int ks = 0; ks < 64; ks++) {        // 2048 / 32
    const int k0 = ks * 32;
#pragma unroll
    for (int q = 0; q < 2; q++) {
      int slot = q * 256 + t;
      int r = slot >> 2;
      int sg = slot & 3;
      int sig = sg ^ ((r >> 1) & 3);       // XOR swizzle (self-inverse)
      size_t go = (size_t)r * 2048 + k0 + sig * 8;
      async16(Ah + baseA + go, sAh + slot * 8);
      async16(Bh + baseB + go, sBh + slot * 8);
    }
    __syncthreads();

    half8 ah[4], bh[4];
#pragma unroll
    for (int mi = 0; mi < 4; mi++) {
      int r = waveM * 64 + mi * 16 + frow;
      int ps = kgrp ^ ((r >> 1) & 3);
      ah[mi] = *(const half8*)(sAh + r * 32 + ps * 8);
    }
#pragma unroll
    for (int ni = 0; ni < 4; ni++) {
      int r = waveN * 64 + ni * 16 + frow;
      int ps = kgrp ^ ((r >> 1) & 3);
      bh[ni] = *(const half8*)(sBh + r * 32 + ps * 8);
    }
#pragma unroll
    for (int mi = 0; mi < 4; mi++)
#pragma unroll
      for (int ni = 0; ni < 4; ni++)
        acc[mi][ni] = __builtin_amdgcn_mfma_f32_16x16x32_f16(ah[mi], bh[ni], acc[mi][ni], 0, 0, 0);
    __syncthreads();
  }

  // epilogue: C/D layout col=lane&15, row=(lane>>4)*4+j (m89-verified)
#pragma unroll
  for (int ni = 0; ni < 4; ni++) {
    int col = nTile * 128 + waveN * 64 + ni * 16 + frow;
    float bias = b_all[col];
#pragma unroll
    for (int mi = 0; mi < 4; mi++) {
      int rbase = mTile * 128 + waveM * 64 + mi * 16 + kgrp * 4;
#pragma unroll
      for (int j = 0; j < 4; j++)
        pre[(size_t)(rbase + j) * 6144 + col] = acc[mi][ni][j] * (1.0f / 64.0f) + bias;
    }
  }
}

// ---------------------------------------------------------------------------
// Row softmax (in place over zft/zit region of pre) + per-chunk column sums.
// CH=8 rows/block; 4 waves x 2 rows; float4 loads/stores; no atomics.
__global__ void softmax_partials(float* __restrict__ pre, float* __restrict__ partials) {
  __shared__ float wsum[4][1024];
  int m = blockIdx.x >> 9;          // 0: zft, 1: zit
  int ch = blockIdx.x & 511;        // chunk of 8 rows
  int t = threadIdx.x;
  int wave = t >> 6, lane = t & 63;
  f32x4 colacc[4] = {};
  for (int rr = 0; rr < 2; rr++) {
    int b = ch * 8 + wave * 2 + rr;
    float* row = pre + (size_t)b * 6144 + (4 + m) * 1024;
    f32x4 v[4];
    float mx = -3.4e38f;
#pragma unroll
    for (int j = 0; j < 4; j++) {
      v[j] = *(const f32x4*)(row + lane * 4 + 256 * j);
      mx = fmaxf(mx, fmaxf(fmaxf(v[j][0], v[j][1]), fmaxf(v[j][2], v[j][3])));
    }
#pragma unroll
    for (int off = 32; off > 0; off >>= 1) mx = fmaxf(mx, __shfl_xor(mx, off, 64));
    float sum = 0.f;
#pragma unroll
    for (int j = 0; j < 4; j++)
#pragma unroll
      for (int q = 0; q < 4; q++) { v[j][q] = __expf(v[j][q] - mx); sum += v[j][q]; }
#pragma unroll
    for (int off = 32; off > 0; off >>= 1) sum += __shfl_xor(sum, off, 64);
    float inv = 1.f / sum;
#pragma unroll
    for (int j = 0; j < 4; j++) {
      v[j] *= inv;
      *(f32x4*)(row + lane * 4 + 256 * j) = v[j];
      colacc[j] += v[j];
    }
  }
#pragma unroll
  for (int j = 0; j < 4; j++)
    *(f32x4*)(&wsum[wave][lane * 4 + 256 * j]) = colacc[j];
  __syncthreads();
  f32x4 s = *(const f32x4*)(&wsum[0][t * 4]);
  s += *(const f32x4*)(&wsum[1][t * 4]);
  s += *(const f32x4*)(&wsum[2][t * 4]);
  s += *(const f32x4*)(&wsum[3][t * 4]);
  *(f32x4*)(partials + ((size_t)m * 512 + ch) * 1024 + t * 4) = s;
}

// Exclusive scan over 512 chunks per (matrix, column): one wave per column.
__global__ void scan_partials(const float* __restrict__ partials, float* __restrict__ offsets) {
  int col = blockIdx.x * 4 + (threadIdx.x >> 6);   // 0..2047 over 2 matrices
  int lane = threadIdx.x & 63;
  int m = col >> 10, c = col & 1023;
  size_t base = (size_t)m * 512 * 1024 + c;
  float v[8];
  float s = 0.f;
#pragma unroll
  for (int j = 0; j < 8; j++) {
    v[j] = partials[base + (size_t)(lane * 8 + j) * 1024];
    s += v[j];
  }
  float incl = s;
#pragma unroll
  for (int off = 1; off < 64; off <<= 1) {
    float o = __shfl_up(incl, off, 64);
    if (lane >= off) incl += o;
  }
  float run = incl - s;                            // exclusive prefix
#pragma unroll
  for (int j = 0; j < 8; j++) {
    offsets[base + (size_t)(lane * 8 + j) * 1024] = run;
    run += v[j];
  }
}

// Final: block = chunk of 8 rows, thread = 4 consecutive cols (float4),
// walk rows accumulating the cumsum, apply gates, write hidden and cell.
__global__ void onlstm_final(const float* __restrict__ pre, const float* __restrict__ cprev,
                             const float* __restrict__ offsets, float* __restrict__ out) {
  int ch = blockIdx.x;              // 0..511
  int c = threadIdx.x * 4;
  f32x4 runf = *(const f32x4*)(offsets + (size_t)ch * 1024 + c);
  f32x4 runi = *(const f32x4*)(offsets + (size_t)(512 + ch) * 1024 + c);
  for (int r = 0; r < 8; r++) {
    int b = ch * 8 + r;
    const float* row = pre + (size_t)b * 6144;
    f32x4 zf = *(const f32x4*)(row + c);
    f32x4 zi = *(const f32x4*)(row + 1024 + c);
    f32x4 zo = *(const f32x4*)(row + 2048 + c);
    f32x4 zc = *(const f32x4*)(row + 3072 + c);
    f32x4 pf = *(const f32x4*)(row + 4096 + c);
    f32x4 pi = *(const f32x4*)(row + 5120 + c);
    f32x4 cp = *(const f32x4*)(cprev + (size_t)b * 1024 + c);
    runf += pf; runi += pi;
    f32x4 hid, cel;
#pragma unroll
    for (int q = 0; q < 4; q++) {
      float ft = runf[q], it = 1.f - runi[q];
      float f  = 1.f / (1.f + __expf(-zf[q]));
      float ii = 1.f / (1.f + __expf(-zi[q]));
      float o  = 1.f / (1.f + __expf(-zo[q]));
      float chat = tanhf(zc[q]);
      float omega = ft * it;
      float fhat = f * omega + (ft - omega);
      float ihat = ii * omega + (it - omega);
      float cell = fhat * cp[q] + ihat * chat;
      hid[q] = o * tanhf(cell);
      cel[q] = cell;
    }
    *(f32x4*)(out + (size_t)b * 1024 + c) = hid;
    *(f32x4*)(out + (size_t)4194304 + (size_t)b * 1024 + c) = cel;   // 4096*1024
  }
}

// ---------------------------------------------------------------------------
extern "C" void kernel_launch(void* const* d_in, const int* in_sizes, int n_in,
                              void* d_out, int out_size, void* d_ws, size_t ws_size,
                              hipStream_t stream) {
  const float* X = (const float*)d_in[0];
  const float* H = (const float*)d_in[1];
  const float* C = (const float*)d_in[2];

  char* ws = (char*)d_ws;
  float*    pre      = (float*)(ws);                      //  96 MB
  _Float16* Ahi      = (_Float16*)(ws + 100663296);       //  16 MB
  _Float16* Bhi      = (_Float16*)(ws + 117440512);       //  24 MB
  float*    b_all    = (float*)(ws + 142606336);          //  24 KB
  float*    partials = (float*)(ws + 142630912);          //   4 MB
  float*    offsets  = (float*)(ws + 146825216);          //   4 MB

  Ptrs12 w;
  for (int g = 0; g < 6; g++) {
    w.p[2 * g]     = (const float*)d_in[3 + 3 * g];   // Wg
    w.p[2 * g + 1] = (const float*)d_in[4 + 3 * g];   // Ug
  }
  Ptrs6 bs;
  for (int g = 0; g < 6; g++) bs.p[g] = (const float*)d_in[5 + 3 * g];

  prep<<<11288, 256, 0, stream>>>(X, H, w, bs, Ahi, Bhi, b_all);
  gemm_split<<<1536, 256, 0, stream>>>(Ahi, Bhi, b_all, pre);
  softmax_partials<<<1024, 256, 0, stream>>>(pre, partials);
  scan_partials<<<512, 256, 0, stream>>>(partials, offsets);
  onlstm_final<<<512, 256, 0, stream>>>(pre, C, offsets, (float*)d_out);
}

// Round 5
// 344.844 us; speedup vs baseline: 1.5907x; 1.0028x over previous
//
#include <hip/hip_runtime.h>
#include <cstdint>
#include <cstddef>

// ONLSTM cell: B=4096, D=1024, U=1024.
// pre = [X|H] @ [[W_all],[U_all]] + b_all, single-fp16 MFMA (m97 structure).
// R1-R4 verified: absmax (0.25) dominated by fp32 softmax/cumsum path, not GEMM
// precision; threshold 1.55.
// R5: gates stored fp16 (preG), softmax input fp32 (preS), softmax p fp16 (P);
// partials/offsets in transposed [m][c4][ch] f32x4 layout so the batch-axis
// scan is coalesced; prep B-transpose uses 16 B stores.

typedef _Float16 half8  __attribute__((ext_vector_type(8)));
typedef _Float16 half4v __attribute__((ext_vector_type(4)));
typedef float f32x4 __attribute__((ext_vector_type(4)));

__device__ __forceinline__ void async16(const _Float16* g, _Float16* l) {
  __builtin_amdgcn_global_load_lds(
      (const __attribute__((address_space(1))) void*)g,
      (__attribute__((address_space(3))) void*)l, 16, 0, 0);
}

struct Ptrs12 { const float* p[12]; };
struct Ptrs6  { const float* p[6];  };

// ---------------------------------------------------------------------------
// Merged prep: convert A (X|H -> fp16), convert+transpose B (x64 scale, fp16),
// build bias. Branch is block-uniform.
__global__ void prep(const float* __restrict__ X, const float* __restrict__ H,
                     Ptrs12 w, Ptrs6 bs,
                     _Float16* __restrict__ Ahi, _Float16* __restrict__ Bhi,
                     float* __restrict__ b_all) {
  __shared__ float tile[64][65];
  const int blk = blockIdx.x;
  const int t = threadIdx.x;
  if (blk < 8192) {
    // ---- convert_A: 4 consecutive elements per thread (never crosses X/H split)
    size_t base = ((size_t)blk * 256 + t) * 4;       // < 4096*2048
    int k = (int)(base & 2047);
    size_t b = base >> 11;
    const float* src = (k < 1024) ? (X + b * 1024 + k) : (H + b * 1024 + (k - 1024));
    float4 v = *(const float4*)src;
    half4v hi = { (_Float16)v.x, (_Float16)v.y, (_Float16)v.z, (_Float16)v.w };
    *(half4v*)(Ahi + base) = hi;
  } else if (blk < 11264) {
    // ---- convert_B: transpose 64x64 tile through LDS, x64 scale (guard vs
    // fp16 subnormal flush in MFMA; /64 folded into epilogue). 16 B stores.
    int bb = blk - 8192;
    int mat = bb >> 8;                 // 0..11 == g*2 + s
    int tl = bb & 255;
    int tr = tl >> 4, tc = tl & 15;    // tr: k-block, tc: c-block
    int g = mat >> 1, s = mat & 1;
    const float* src = w.p[mat];
    int col = t & 63, r0 = t >> 6;
#pragma unroll
    for (int i = 0; i < 16; i++) {
      int row = i * 4 + r0;            // row = k index, col = c index
      tile[row][col] = src[(size_t)(tr * 64 + row) * 1024 + tc * 64 + col];
    }
    __syncthreads();
    int c2 = t >> 2, kseg = t & 3;     // 16 k per thread, contiguous
    half8 v0, v1;
#pragma unroll
    for (int j = 0; j < 8; j++) {
      v0[j] = (_Float16)(tile[kseg * 16 + j][c2] * 64.0f);
      v1[j] = (_Float16)(tile[kseg * 16 + 8 + j][c2] * 64.0f);
    }
    size_t n  = (size_t)g * 1024 + tc * 64 + c2;
    size_t kk = (size_t)s * 1024 + tr * 64 + kseg * 16;
    *(half8*)(Bhi + n * 2048 + kk) = v0;
    *(half8*)(Bhi + n * 2048 + kk + 8) = v1;
  } else {
    int n = (blk - 11264) * 256 + t;    // < 6144
    b_all[n] = bs.p[n >> 10][n & 1023];
  }
}

// ---------------------------------------------------------------------------
// GEMM: A[M=4096,2048] @ Bt[6144,2048]^T / 64 + bias.
// m97 structure: 128x128 tile, BK=32, 4 waves of 64x64, 16 KB LDS.
// nTile<32 -> gates, fp16 into preG[4096][4096]; else fp32 into preS[4096][2048].
__global__ __launch_bounds__(256) void gemm_split(
    const _Float16* __restrict__ Ah, const _Float16* __restrict__ Bh,
    const float* __restrict__ b_all,
    _Float16* __restrict__ preG, float* __restrict__ preS) {
  __shared__ _Float16 lds[8192];   // 16 KB: A tile + B tile
  _Float16* sAh = lds;
  _Float16* sBh = lds + 4096;

  // GROUP_M=8 swizzle: 8 consecutive pids share one B tile (L2 reuse)
  const int pid = blockIdx.x;                 // 0..1535
  const int group = pid / (8 * 48);
  const int rem = pid % (8 * 48);
  const int mTile = group * 8 + (rem & 7);    // 0..31
  const int nTile = rem >> 3;                 // 0..47

  const int t = threadIdx.x;
  const int lane = t & 63;
  const int wave = t >> 6;
  const int waveM = wave >> 1, waveN = wave & 1;
  const int kgrp = lane >> 4, frow = lane & 15;
  const size_t baseA = (size_t)mTile * 128 * 2048;
  const size_t baseB = (size_t)nTile * 128 * 2048;

  f32x4 acc[4][4] = {};

  for (int ks = 0; ks < 64; ks++) {        // 2048 / 32
    const int k0 = ks * 32;
#pragma unroll
    for (int q = 0; q < 2; q++) {
      int slot = q * 256 + t;
      int r = slot >> 2;
      int sg = slot & 3;
      int sig = sg ^ ((r >> 1) & 3);       // XOR swizzle (self-inverse)
      size_t go = (size_t)r * 2048 + k0 + sig * 8;
      async16(Ah + baseA + go, sAh + slot * 8);
      async16(Bh + baseB + go, sBh + slot * 8);
    }
    __syncthreads();

    half8 ah[4], bh[4];
#pragma unroll
    for (int mi = 0; mi < 4; mi++) {
      int r = waveM * 64 + mi * 16 + frow;
      int ps = kgrp ^ ((r >> 1) & 3);
      ah[mi] = *(const half8*)(sAh + r * 32 + ps * 8);
    }
#pragma unroll
    for (int ni = 0; ni < 4; ni++) {
      int r = waveN * 64 + ni * 16 + frow;
      int ps = kgrp ^ ((r >> 1) & 3);
      bh[ni] = *(const half8*)(sBh + r * 32 + ps * 8);
    }
#pragma unroll
    for (int mi = 0; mi < 4; mi++)
#pragma unroll
      for (int ni = 0; ni < 4; ni++)
        acc[mi][ni] = __builtin_amdgcn_mfma_f32_16x16x32_f16(ah[mi], bh[ni], acc[mi][ni], 0, 0, 0);
    __syncthreads();
  }

  // epilogue: C/D layout col=lane&15, row=(lane>>4)*4+j (m89-verified)
  if (nTile < 32) {
#pragma unroll
    for (int ni = 0; ni < 4; ni++) {
      int col = nTile * 128 + waveN * 64 + ni * 16 + frow;
      float bias = b_all[col];
#pragma unroll
      for (int mi = 0; mi < 4; mi++) {
        int rbase = mTile * 128 + waveM * 64 + mi * 16 + kgrp * 4;
#pragma unroll
        for (int j = 0; j < 4; j++)
          preG[(size_t)(rbase + j) * 4096 + col] =
              (_Float16)(acc[mi][ni][j] * (1.0f / 64.0f) + bias);
      }
    }
  } else {
#pragma unroll
    for (int ni = 0; ni < 4; ni++) {
      int col = (nTile - 32) * 128 + waveN * 64 + ni * 16 + frow;
      float bias = b_all[4096 + col];
#pragma unroll
      for (int mi = 0; mi < 4; mi++) {
        int rbase = mTile * 128 + waveM * 64 + mi * 16 + kgrp * 4;
#pragma unroll
        for (int j = 0; j < 4; j++)
          preS[(size_t)(rbase + j) * 2048 + col] =
              acc[mi][ni][j] * (1.0f / 64.0f) + bias;
      }
    }
  }
}

// ---------------------------------------------------------------------------
// Row softmax over preS -> p (fp16, P[2][4096][1024]) + per-chunk column sums
// into transposed layout part4[(m*256 + c4)*512 + ch] (f32x4 over 4 columns).
// CH=8 rows/block; 4 waves x 2 rows; no atomics.
__global__ void softmax_partials(const float* __restrict__ preS,
                                 _Float16* __restrict__ P, f32x4* __restrict__ part4) {
  __shared__ float wsum[4][1024];
  int m = blockIdx.x >> 9;          // 0: zft, 1: zit
  int ch = blockIdx.x & 511;        // chunk of 8 rows
  int t = threadIdx.x;
  int wave = t >> 6, lane = t & 63;
  f32x4 colacc[4] = {};
  for (int rr = 0; rr < 2; rr++) {
    int b = ch * 8 + wave * 2 + rr;
    const float* row = preS + (size_t)b * 2048 + m * 1024;
    _Float16* prow = P + ((size_t)m * 4096 + b) * 1024;
    f32x4 v[4];
    float mx = -3.4e38f;
#pragma unroll
    for (int j = 0; j < 4; j++) {
      v[j] = *(const f32x4*)(row + lane * 4 + 256 * j);
      mx = fmaxf(mx, fmaxf(fmaxf(v[j][0], v[j][1]), fmaxf(v[j][2], v[j][3])));
    }
#pragma unroll
    for (int off = 32; off > 0; off >>= 1) mx = fmaxf(mx, __shfl_xor(mx, off, 64));
    float sum = 0.f;
#pragma unroll
    for (int j = 0; j < 4; j++)
#pragma unroll
      for (int q = 0; q < 4; q++) { v[j][q] = __expf(v[j][q] - mx); sum += v[j][q]; }
#pragma unroll
    for (int off = 32; off > 0; off >>= 1) sum += __shfl_xor(sum, off, 64);
    float inv = 1.f / sum;
#pragma unroll
    for (int j = 0; j < 4; j++) {
      v[j] *= inv;
      half4v h = { (_Float16)v[j][0], (_Float16)v[j][1], (_Float16)v[j][2], (_Float16)v[j][3] };
      *(half4v*)(prow + lane * 4 + 256 * j) = h;
      colacc[j] += v[j];
    }
  }
#pragma unroll
  for (int j = 0; j < 4; j++)
    *(f32x4*)(&wsum[wave][lane * 4 + 256 * j]) = colacc[j];
  __syncthreads();
  f32x4 s = *(const f32x4*)(&wsum[0][t * 4]);
  s += *(const f32x4*)(&wsum[1][t * 4]);
  s += *(const f32x4*)(&wsum[2][t * 4]);
  s += *(const f32x4*)(&wsum[3][t * 4]);
  part4[((size_t)m * 256 + t) * 512 + ch] = s;    // transposed: [m][c4][ch]
}

// Exclusive scan over 512 chunks per (m, c4-group): one wave per group,
// fully coalesced (contiguous 8 KB per wave in the transposed layout).
__global__ void scan_partials(const f32x4* __restrict__ part4, f32x4* __restrict__ off4) {
  int gidx = blockIdx.x * 4 + (threadIdx.x >> 6);   // 0..511 (m*256 + c4)
  int lane = threadIdx.x & 63;
  size_t base = (size_t)gidx * 512;
  f32x4 v[8];
  f32x4 s = {};
#pragma unroll
  for (int j = 0; j < 8; j++) {
    v[j] = part4[base + lane * 8 + j];
    s += v[j];
  }
  f32x4 incl = s;
#pragma unroll
  for (int off = 1; off < 64; off <<= 1) {
    f32x4 o;
#pragma unroll
    for (int q = 0; q < 4; q++) o[q] = __shfl_up(incl[q], off, 64);
    if (lane >= off) incl += o;
  }
  f32x4 run = incl - s;                            // exclusive prefix
#pragma unroll
  for (int j = 0; j < 8; j++) {
    off4[base + lane * 8 + j] = run;
    run += v[j];
  }
}

// Final: block = chunk of 8 rows, thread = 4 consecutive cols, walk rows
// accumulating the cumsum, apply gates, write hidden and cell.
__global__ void onlstm_final(const _Float16* __restrict__ preG, const _Float16* __restrict__ P,
                             const float* __restrict__ cprev, const f32x4* __restrict__ off4,
                             float* __restrict__ out) {
  int ch = blockIdx.x;              // 0..511
  int c4 = threadIdx.x;
  int c = c4 * 4;
  f32x4 runf = off4[(size_t)c4 * 512 + ch];
  f32x4 runi = off4[(size_t)(256 + c4) * 512 + ch];
  for (int r = 0; r < 8; r++) {
    int b = ch * 8 + r;
    const _Float16* grow = preG + (size_t)b * 4096;
    half4v zf = *(const half4v*)(grow + c);
    half4v zi = *(const half4v*)(grow + 1024 + c);
    half4v zo = *(const half4v*)(grow + 2048 + c);
    half4v zc = *(const half4v*)(grow + 3072 + c);
    half4v pf = *(const half4v*)(P + (size_t)b * 1024 + c);
    half4v pi = *(const half4v*)(P + (size_t)(4096 + b) * 1024 + c);
    f32x4 cp = *(const f32x4*)(cprev + (size_t)b * 1024 + c);
    f32x4 hid, cel;
#pragma unroll
    for (int q = 0; q < 4; q++) {
      runf[q] += (float)pf[q];
      runi[q] += (float)pi[q];
      float ft = runf[q], it = 1.f - runi[q];
      float f  = 1.f / (1.f + __expf(-(float)zf[q]));
      float ii = 1.f / (1.f + __expf(-(float)zi[q]));
      float o  = 1.f / (1.f + __expf(-(float)zo[q]));
      float chat = tanhf((float)zc[q]);
      float omega = ft * it;
      float fhat = f * omega + (ft - omega);
      float ihat = ii * omega + (it - omega);
      float cell = fhat * cp[q] + ihat * chat;
      hid[q] = o * tanhf(cell);
      cel[q] = cell;
    }
    *(f32x4*)(out + (size_t)b * 1024 + c) = hid;
    *(f32x4*)(out + (size_t)4194304 + (size_t)b * 1024 + c) = cel;   // 4096*1024
  }
}

// ---------------------------------------------------------------------------
extern "C" void kernel_launch(void* const* d_in, const int* in_sizes, int n_in,
                              void* d_out, int out_size, void* d_ws, size_t ws_size,
                              hipStream_t stream) {
  const float* X = (const float*)d_in[0];
  const float* H = (const float*)d_in[1];
  const float* C = (const float*)d_in[2];

  char* ws = (char*)d_ws;
  _Float16* preG  = (_Float16*)(ws);                      // 32 MB [4096][4096]
  float*    preS  = (float*)(ws + 33554432);              // 32 MB [4096][2048]
  _Float16* Ahi   = (_Float16*)(ws + 67108864);           // 16 MB
  _Float16* Bhi   = (_Float16*)(ws + 83886080);           // 24 MB
  _Float16* P     = (_Float16*)(ws + 109051904);          // 16 MB [2][4096][1024]
  float*    b_all = (float*)(ws + 125829120);             // 24 KB
  f32x4*    part4 = (f32x4*)(ws + 125853696);             //  4 MB [2][256][512] x4
  f32x4*    off4  = (f32x4*)(ws + 130048000);             //  4 MB

  Ptrs12 w;
  for (int g = 0; g < 6; g++) {
    w.p[2 * g]     = (const float*)d_in[3 + 3 * g];   // Wg
    w.p[2 * g + 1] = (const float*)d_in[4 + 3 * g];   // Ug
  }
  Ptrs6 bs;
  for (int g = 0; g < 6; g++) bs.p[g] = (const float*)d_in[5 + 3 * g];

  prep<<<11288, 256, 0, stream>>>(X, H, w, bs, Ahi, Bhi, b_all);
  gemm_split<<<1536, 256, 0, stream>>>(Ahi, Bhi, b_all, preG, preS);
  softmax_partials<<<1024, 256, 0, stream>>>(preS, P, part4);
  scan_partials<<<128, 256, 0, stream>>>(part4, off4);
  onlstm_final<<<512, 256, 0, stream>>>(preG, P, C, off4, (float*)d_out);
}

// Round 6
// 332.315 us; speedup vs baseline: 1.6506x; 1.0377x over previous
//
#include <hip/hip_runtime.h>
#include <cstdint>
#include <cstddef>

// ONLSTM cell: B=4096, D=1024, U=1024.
// pre16 = fp16([X|H] @ [[W_all],[U_all]] + b_all), single-fp16 MFMA (m97 structure).
// R1-R5 verified: absmax (0.25) dominated by fp32 softmax/cumsum path, not GEMM
// or storage precision (P fp16 changed nothing); threshold 1.55.
// R6: unified fp16 output with LDS-staged coalesced epilogue (R5's scattered
// 32B fp16 stores caused +100MB RMW fetch); softmax p written in place;
// zft/zit stored fp16 too (preS round-trip eliminated).

typedef _Float16 half8  __attribute__((ext_vector_type(8)));
typedef _Float16 half4v __attribute__((ext_vector_type(4)));
typedef float f32x4 __attribute__((ext_vector_type(4)));

__device__ __forceinline__ void async16(const _Float16* g, _Float16* l) {
  __builtin_amdgcn_global_load_lds(
      (const __attribute__((address_space(1))) void*)g,
      (__attribute__((address_space(3))) void*)l, 16, 0, 0);
}

struct Ptrs12 { const float* p[12]; };
struct Ptrs6  { const float* p[6];  };

// ---------------------------------------------------------------------------
// Merged prep: convert A (X|H -> fp16), convert+transpose B (x64 scale, fp16),
// build bias. Branch is block-uniform.
__global__ void prep(const float* __restrict__ X, const float* __restrict__ H,
                     Ptrs12 w, Ptrs6 bs,
                     _Float16* __restrict__ Ahi, _Float16* __restrict__ Bhi,
                     float* __restrict__ b_all) {
  __shared__ float tile[64][65];
  const int blk = blockIdx.x;
  const int t = threadIdx.x;
  if (blk < 8192) {
    // ---- convert_A: 4 consecutive elements per thread (never crosses X/H split)
    size_t base = ((size_t)blk * 256 + t) * 4;       // < 4096*2048
    int k = (int)(base & 2047);
    size_t b = base >> 11;
    const float* src = (k < 1024) ? (X + b * 1024 + k) : (H + b * 1024 + (k - 1024));
    float4 v = *(const float4*)src;
    half4v hi = { (_Float16)v.x, (_Float16)v.y, (_Float16)v.z, (_Float16)v.w };
    *(half4v*)(Ahi + base) = hi;
  } else if (blk < 11264) {
    // ---- convert_B: transpose 64x64 tile through LDS, x64 scale (guard vs
    // fp16 subnormal flush in MFMA; /64 folded into epilogue). 16 B stores.
    int bb = blk - 8192;
    int mat = bb >> 8;                 // 0..11 == g*2 + s
    int tl = bb & 255;
    int tr = tl >> 4, tc = tl & 15;    // tr: k-block, tc: c-block
    int g = mat >> 1, s = mat & 1;
    const float* src = w.p[mat];
    int col = t & 63, r0 = t >> 6;
#pragma unroll
    for (int i = 0; i < 16; i++) {
      int row = i * 4 + r0;            // row = k index, col = c index
      tile[row][col] = src[(size_t)(tr * 64 + row) * 1024 + tc * 64 + col];
    }
    __syncthreads();
    int c2 = t >> 2, kseg = t & 3;     // 16 k per thread, contiguous
    half8 v0, v1;
#pragma unroll
    for (int j = 0; j < 8; j++) {
      v0[j] = (_Float16)(tile[kseg * 16 + j][c2] * 64.0f);
      v1[j] = (_Float16)(tile[kseg * 16 + 8 + j][c2] * 64.0f);
    }
    size_t n  = (size_t)g * 1024 + tc * 64 + c2;
    size_t kk = (size_t)s * 1024 + tr * 64 + kseg * 16;
    *(half8*)(Bhi + n * 2048 + kk) = v0;
    *(half8*)(Bhi + n * 2048 + kk + 8) = v1;
  } else {
    int n = (blk - 11264) * 256 + t;    // < 6144
    b_all[n] = bs.p[n >> 10][n & 1023];
  }
}

// ---------------------------------------------------------------------------
// GEMM: A[M=4096,2048] @ Bt[6144,2048]^T / 64 + bias -> pre16 (fp16, row-major).
// m97 structure: 128x128 tile, BK=32, 4 waves of 64x64.
// Epilogue: per 64-row half, stage fp16 tile in LDS (stride 136 halves, padded),
// then cooperatively store full 256 B row-chunks (no partial-line RMW).
__global__ __launch_bounds__(256) void gemm_split(
    const _Float16* __restrict__ Ah, const _Float16* __restrict__ Bh,
    const float* __restrict__ b_all, _Float16* __restrict__ pre16) {
  __shared__ _Float16 lds[64 * 136];   // 17 KB; staging uses first 8192 halves
  _Float16* sAh = lds;
  _Float16* sBh = lds + 4096;

  // GROUP_M=8 swizzle: 8 consecutive pids share one B tile (L2 reuse)
  const int pid = blockIdx.x;                 // 0..1535
  const int group = pid / (8 * 48);
  const int rem = pid % (8 * 48);
  const int mTile = group * 8 + (rem & 7);    // 0..31
  const int nTile = rem >> 3;                 // 0..47

  const int t = threadIdx.x;
  const int lane = t & 63;
  const int wave = t >> 6;
  const int waveM = wave >> 1, waveN = wave & 1;
  const int kgrp = lane >> 4, frow = lane & 15;
  const size_t baseA = (size_t)mTile * 128 * 2048;
  const size_t baseB = (size_t)nTile * 128 * 2048;

  f32x4 acc[4][4] = {};

  for (int ks = 0; ks < 64; ks++) {        // 2048 / 32
    const int k0 = ks * 32;
#pragma unroll
    for (int q = 0; q < 2; q++) {
      int slot = q * 256 + t;
      int r = slot >> 2;
      int sg = slot & 3;
      int sig = sg ^ ((r >> 1) & 3);       // XOR swizzle (self-inverse)
      size_t go = (size_t)r * 2048 + k0 + sig * 8;
      async16(Ah + baseA + go, sAh + slot * 8);
      async16(Bh + baseB + go, sBh + slot * 8);
    }
    __syncthreads();

    half8 ah[4], bh[4];
#pragma unroll
    for (int mi = 0; mi < 4; mi++) {
      int r = waveM * 64 + mi * 16 + frow;
      int ps = kgrp ^ ((r >> 1) & 3);
      ah[mi] = *(const half8*)(sAh + r * 32 + ps * 8);
    }
#pragma unroll
    for (int ni = 0; ni < 4; ni++) {
      int r = waveN * 64 + ni * 16 + frow;
      int ps = kgrp ^ ((r >> 1) & 3);
      bh[ni] = *(const half8*)(sBh + r * 32 + ps * 8);
    }
#pragma unroll
    for (int mi = 0; mi < 4; mi++)
#pragma unroll
      for (int ni = 0; ni < 4; ni++)
        acc[mi][ni] = __builtin_amdgcn_mfma_f32_16x16x32_f16(ah[mi], bh[ni], acc[mi][ni], 0, 0, 0);
    __syncthreads();
  }

  // epilogue: acc C/D layout col=lane&15, row=(lane>>4)*4+j (m89-verified).
  const int cbase = nTile * 128;
  float bias[4];
#pragma unroll
  for (int ni = 0; ni < 4; ni++)
    bias[ni] = b_all[cbase + waveN * 64 + ni * 16 + frow];

#pragma unroll
  for (int pass = 0; pass < 2; pass++) {
    if (waveM == pass) {
#pragma unroll
      for (int mi = 0; mi < 4; mi++)
#pragma unroll
        for (int ni = 0; ni < 4; ni++) {
          int colL = waveN * 64 + ni * 16 + frow;
#pragma unroll
          for (int j = 0; j < 4; j++) {
            int rowL = mi * 16 + kgrp * 4 + j;
            lds[rowL * 136 + colL] =
                (_Float16)(acc[mi][ni][j] * (1.0f / 64.0f) + bias[ni]);
          }
        }
    }
    __syncthreads();
    // cooperative store: 4 rounds x (16 rows x 128 cols), 256 B/row contiguous
#pragma unroll
    for (int rnd = 0; rnd < 4; rnd++) {
      int row = rnd * 16 + (t >> 4);
      int seg = t & 15;
      half8 v = *(const half8*)(lds + row * 136 + seg * 8);
      *(half8*)(pre16 + (size_t)(mTile * 128 + pass * 64 + row) * 6144 + cbase + seg * 8) = v;
    }
    __syncthreads();
  }
}

// ---------------------------------------------------------------------------
// Row softmax over zft/zit (fp16 in pre16, cols 4096..6143), p written back in
// place (fp16) + per-chunk column sums into transposed part4[(m*256+c4)*512+ch].
// CH=8 rows/block; 4 waves x 2 rows; no atomics.
__global__ void softmax_partials(_Float16* __restrict__ pre16, f32x4* __restrict__ part4) {
  __shared__ float wsum[4][1024];
  int m = blockIdx.x >> 9;          // 0: zft, 1: zit
  int ch = blockIdx.x & 511;        // chunk of 8 rows
  int t = threadIdx.x;
  int wave = t >> 6, lane = t & 63;
  f32x4 colacc[4] = {};
  for (int rr = 0; rr < 2; rr++) {
    int b = ch * 8 + wave * 2 + rr;
    _Float16* row = pre16 + (size_t)b * 6144 + (4 + m) * 1024;
    f32x4 v[4];
    float mx = -3.4e38f;
#pragma unroll
    for (int j = 0; j < 4; j++) {
      half4v h = *(const half4v*)(row + lane * 4 + 256 * j);
      v[j] = f32x4{ (float)h[0], (float)h[1], (float)h[2], (float)h[3] };
      mx = fmaxf(mx, fmaxf(fmaxf(v[j][0], v[j][1]), fmaxf(v[j][2], v[j][3])));
    }
#pragma unroll
    for (int off = 32; off > 0; off >>= 1) mx = fmaxf(mx, __shfl_xor(mx, off, 64));
    float sum = 0.f;
#pragma unroll
    for (int j = 0; j < 4; j++)
#pragma unroll
      for (int q = 0; q < 4; q++) { v[j][q] = __expf(v[j][q] - mx); sum += v[j][q]; }
#pragma unroll
    for (int off = 32; off > 0; off >>= 1) sum += __shfl_xor(sum, off, 64);
    float inv = 1.f / sum;
#pragma unroll
    for (int j = 0; j < 4; j++) {
      v[j] *= inv;
      half4v h = { (_Float16)v[j][0], (_Float16)v[j][1], (_Float16)v[j][2], (_Float16)v[j][3] };
      *(half4v*)(row + lane * 4 + 256 * j) = h;
      colacc[j] += v[j];
    }
  }
#pragma unroll
  for (int j = 0; j < 4; j++)
    *(f32x4*)(&wsum[wave][lane * 4 + 256 * j]) = colacc[j];
  __syncthreads();
  f32x4 s = *(const f32x4*)(&wsum[0][t * 4]);
  s += *(const f32x4*)(&wsum[1][t * 4]);
  s += *(const f32x4*)(&wsum[2][t * 4]);
  s += *(const f32x4*)(&wsum[3][t * 4]);
  part4[((size_t)m * 256 + t) * 512 + ch] = s;    // transposed: [m][c4][ch]
}

// Exclusive scan over 512 chunks per (m, c4-group): one wave per group,
// fully coalesced (contiguous 8 KB per wave in the transposed layout).
__global__ void scan_partials(const f32x4* __restrict__ part4, f32x4* __restrict__ off4) {
  int gidx = blockIdx.x * 4 + (threadIdx.x >> 6);   // 0..511 (m*256 + c4)
  int lane = threadIdx.x & 63;
  size_t base = (size_t)gidx * 512;
  f32x4 v[8];
  f32x4 s = {};
#pragma unroll
  for (int j = 0; j < 8; j++) {
    v[j] = part4[base + lane * 8 + j];
    s += v[j];
  }
  f32x4 incl = s;
#pragma unroll
  for (int off = 1; off < 64; off <<= 1) {
    f32x4 o;
#pragma unroll
    for (int q = 0; q < 4; q++) o[q] = __shfl_up(incl[q], off, 64);
    if (lane >= off) incl += o;
  }
  f32x4 run = incl - s;                            // exclusive prefix
#pragma unroll
  for (int j = 0; j < 8; j++) {
    off4[base + lane * 8 + j] = run;
    run += v[j];
  }
}

// Final: block = chunk of 8 rows, thread = 4 consecutive cols; reads the whole
// 12 KB pre16 row stream (gates + in-place p), accumulates cumsum, writes out.
__global__ void onlstm_final(const _Float16* __restrict__ pre16,
                             const float* __restrict__ cprev, const f32x4* __restrict__ off4,
                             float* __restrict__ out) {
  int ch = blockIdx.x;              // 0..511
  int c4 = threadIdx.x;
  int c = c4 * 4;
  f32x4 runf = off4[(size_t)c4 * 512 + ch];
  f32x4 runi = off4[(size_t)(256 + c4) * 512 + ch];
  for (int r = 0; r < 8; r++) {
    int b = ch * 8 + r;
    const _Float16* row = pre16 + (size_t)b * 6144;
    half4v zf = *(const half4v*)(row + c);
    half4v zi = *(const half4v*)(row + 1024 + c);
    half4v zo = *(const half4v*)(row + 2048 + c);
    half4v zc = *(const half4v*)(row + 3072 + c);
    half4v pf = *(const half4v*)(row + 4096 + c);
    half4v pi = *(const half4v*)(row + 5120 + c);
    f32x4 cp = *(const f32x4*)(cprev + (size_t)b * 1024 + c);
    f32x4 hid, cel;
#pragma unroll
    for (int q = 0; q < 4; q++) {
      runf[q] += (float)pf[q];
      runi[q] += (float)pi[q];
      float ft = runf[q], it = 1.f - runi[q];
      float f  = 1.f / (1.f + __expf(-(float)zf[q]));
      float ii = 1.f / (1.f + __expf(-(float)zi[q]));
      float o  = 1.f / (1.f + __expf(-(float)zo[q]));
      float chat = tanhf((float)zc[q]);
      float omega = ft * it;
      float fhat = f * omega + (ft - omega);
      float ihat = ii * omega + (it - omega);
      float cell = fhat * cp[q] + ihat * chat;
      hid[q] = o * tanhf(cell);
      cel[q] = cell;
    }
    *(f32x4*)(out + (size_t)b * 1024 + c) = hid;
    *(f32x4*)(out + (size_t)4194304 + (size_t)b * 1024 + c) = cel;   // 4096*1024
  }
}

// ---------------------------------------------------------------------------
extern "C" void kernel_launch(void* const* d_in, const int* in_sizes, int n_in,
                              void* d_out, int out_size, void* d_ws, size_t ws_size,
                              hipStream_t stream) {
  const float* X = (const float*)d_in[0];
  const float* H = (const float*)d_in[1];
  const float* C = (const float*)d_in[2];

  char* ws = (char*)d_ws;
  _Float16* pre16 = (_Float16*)(ws);                      // 48 MB [4096][6144]
  _Float16* Ahi   = (_Float16*)(ws + 50331648);           // 16 MB
  _Float16* Bhi   = (_Float16*)(ws + 67108864);           // 24 MB
  float*    b_all = (float*)(ws + 92274688);              // 24 KB
  f32x4*    part4 = (f32x4*)(ws + 92299264);              //  4 MB [2][256][512] x4
  f32x4*    off4  = (f32x4*)(ws + 96493568);              //  4 MB

  Ptrs12 w;
  for (int g = 0; g < 6; g++) {
    w.p[2 * g]     = (const float*)d_in[3 + 3 * g];   // Wg
    w.p[2 * g + 1] = (const float*)d_in[4 + 3 * g];   // Ug
  }
  Ptrs6 bs;
  for (int g = 0; g < 6; g++) bs.p[g] = (const float*)d_in[5 + 3 * g];

  prep<<<11288, 256, 0, stream>>>(X, H, w, bs, Ahi, Bhi, b_all);
  gemm_split<<<1536, 256, 0, stream>>>(Ahi, Bhi, b_all, pre16);
  softmax_partials<<<1024, 256, 0, stream>>>(pre16, part4);
  scan_partials<<<128, 256, 0, stream>>>(part4, off4);
  onlstm_final<<<512, 256, 0, stream>>>(pre16, C, off4, (float*)d_out);
}